// Round 7
// baseline (193.912 us; speedup 1.0000x reference)
//
#include <hip/hip_runtime.h>
#include <math.h>

#define BATCH 64
#define HIMG 224
#define WIMG 224
#define IMGPLANE (HIMG*WIMG)   // 50176
#define CF 512
#define HF 28
#define WF 28
#define POS (HF*WF)            // 784
#define ALPHA_C 0.15f
#define EPS_C 1e-6f

#define STRIPS 14              // 16-row strips per sample
#define SROWS 16
#define GROWS 20               // SROWS + 4 halo rows
#define GSTR 229               // LDS row stride for gray (odd)
#define VSTR 261               // LDS row stride for var (swizzled cols)
#define SHN 4580               // max(GROWS*GSTR=4580, SROWS*VSTR=4176)

#define ZG 16                  // channel groups
#define ZCH 32                 // channels per group (short serial chains!)

// ---- ws layout (in floats) ----
#define OFF_HRES 0
#define HRES_CNT (BATCH*HIMG*WF)             // 401,408
#define OFF_BMM (OFF_HRES + HRES_CNT)        // BATCH*STRIPS*2 per-strip [min,max]
#define OFF_AP  (OFF_BMM + BATCH*STRIPS*2)   // ZG*BATCH*POS partial channel sums
#define OFF_ACC (OFF_AP + ZG*BATCH*POS)      // loss accumulator
#define OFF_CNT (OFF_ACC + 1)                // done counter (uint slot)

// ---- attn partials: block (z,b) sums 32 channels; 16 partials per (b,p).
// Chain per thread = 32 float4 loads -> latency*chain small; 1024 blocks give TLP.
__global__ __launch_bounds__(256) void attn_k(const float* __restrict__ f,
                                              float* __restrict__ ws) {
    int z = blockIdx.x, b = blockIdx.y;
    int tid = threadIdx.x;
    if (z == 0 && b == 0 && tid == 0) {
        ws[OFF_ACC] = 0.0f;
        ((unsigned*)ws)[OFF_CNT] = 0u;
    }
    if (tid >= 196) return;     // 196 float4 per plane
    const float* fp = f + (size_t)(b * CF + z * ZCH) * POS + 4 * tid;
    float ax = 0.0f, ay = 0.0f, az = 0.0f, aw = 0.0f;
    #pragma unroll
    for (int c = 0; c < ZCH; c++) {
        float4 u = *(const float4*)(fp + (size_t)c * POS);
        ax += u.x * u.x; ay += u.y * u.y;
        az += u.z * u.z; aw += u.w * u.w;
    }
    *(float4*)(ws + OFF_AP + (size_t)(z * BATCH + b) * POS + 4 * tid) =
        make_float4(ax, ay, az, aw);
}

// ---- gray -> 5x5 box var (ring-buffer column sums) -> horizontal 16-tap resize ----
__global__ __launch_bounds__(256) void varh_k(const float* __restrict__ img,
                                              float* __restrict__ ws) {
    __shared__ float sh[SHN];   // gray, later overlaid with var (18,320 B)
    __shared__ float wred[8];
    int sy = blockIdx.x, b = blockIdx.y;
    int tid = threadIdx.x;
    int y0 = sy * SROWS;
    const float* imb = img + (size_t)b * 3 * IMGPLANE;

    // stage gray interior via float4 (rows 16B-aligned: 224 floats/row)
    for (int i = tid; i < GROWS * 56; i += 256) {
        int gr = i / 56, q = i - gr * 56;
        int gy = y0 - 2 + gr;
        float gx0 = 0.0f, gx1 = 0.0f, gx2 = 0.0f, gx3 = 0.0f;
        if ((unsigned)gy < HIMG) {
            const float* row = imb + gy * WIMG + 4 * q;
            float4 a = *(const float4*)(row);
            float4 bb = *(const float4*)(row + IMGPLANE);
            float4 c = *(const float4*)(row + 2 * IMGPLANE);
            gx0 = 0.299f * a.x + 0.587f * bb.x + 0.114f * c.x;
            gx1 = 0.299f * a.y + 0.587f * bb.y + 0.114f * c.y;
            gx2 = 0.299f * a.z + 0.587f * bb.z + 0.114f * c.z;
            gx3 = 0.299f * a.w + 0.587f * bb.w + 0.114f * c.w;
        }
        int base = gr * GSTR + 2 + 4 * q;
        sh[base] = gx0; sh[base + 1] = gx1; sh[base + 2] = gx2; sh[base + 3] = gx3;
    }
    // zero gray col-halo (cols 0,1,226,227)
    if (tid < GROWS * 4) {
        int gr = tid >> 2, p = tid & 3;
        int gc = (p < 2) ? p : (224 + p);
        sh[gr * GSTR + gc] = 0.0f;
    }
    __syncthreads();

    // var into registers: thread (r = tid>>4, 14-col segment s = tid&15)
    int r = tid >> 4, s = tid & 15;
    int x0 = 14 * s;
    const float* gr0 = sh + r * GSTR;
    float c1[5], c2[5], vreg[14];
    #pragma unroll
    for (int m = 0; m < 5; m++) {
        float a = 0.0f, a2 = 0.0f;
        #pragma unroll
        for (int k = 0; k < 5; k++) {
            float u = gr0[k * GSTR + x0 + m];
            a += u; a2 += u * u;
        }
        c1[m] = a; c2[m] = a2;
    }
    float vmn = INFINITY, vmx = 0.0f;
    #pragma unroll
    for (int xi = 0; xi < 14; xi++) {
        int p = xi % 5;
        float s1 = c1[p], s2 = c2[p];
        #pragma unroll
        for (int m = 1; m < 5; m++) {
            s1 += c1[(p + m) % 5];
            s2 += c2[(p + m) % 5];
        }
        float m1 = s1 * 0.04f, m2 = s2 * 0.04f;
        float vv = fmaxf(m2 - m1 * m1, 0.0f);
        vreg[xi] = vv;
        vmn = fminf(vmn, vv); vmx = fmaxf(vmx, vv);
        if (xi < 13) {
            float a = 0.0f, a2 = 0.0f;
            #pragma unroll
            for (int k = 0; k < 5; k++) {
                float u = gr0[k * GSTR + x0 + xi + 5];
                a += u; a2 += u * u;
            }
            c1[p] = a; c2[p] = a2;
        }
    }
    #pragma unroll
    for (int o = 32; o > 0; o >>= 1) {
        vmn = fminf(vmn, __shfl_xor(vmn, o));
        vmx = fmaxf(vmx, __shfl_xor(vmx, o));
    }
    __syncthreads();   // all gray reads done -> safe to overlay with var
    int w = tid >> 6;
    if ((tid & 63) == 0) { wred[w] = vmn; wred[4 + w] = vmx; }
    // zero var col-halo (jh 0..3 and 228..231)
    if (tid < SROWS * 8) {
        int rr = tid >> 3, p = tid & 7;
        int jh = p + ((p < 4) ? 0 : 224);
        sh[rr * VSTR + jh + (jh >> 3)] = 0.0f;
    }
    // write var registers into overlaid buffer (swizzled cols)
    #pragma unroll
    for (int xi = 0; xi < 14; xi++) {
        int jh = x0 + xi + 4;
        sh[r * VSTR + jh + (jh >> 3)] = vreg[xi];
    }
    __syncthreads();   // var + wred ready
    if (tid == 0) {
        float mn = fminf(fminf(wred[0], wred[1]), fminf(wred[2], wred[3]));
        float mx = fmaxf(fmaxf(wred[4], wred[5]), fmaxf(wred[6], wred[7]));
        int blk = b * STRIPS + sy;
        ws[OFF_BMM + 2 * blk]     = mn;
        ws[OFF_BMM + 2 * blk + 1] = mx;
    }

    // horizontal 16-tap resize from LDS var; coalesced store of hres strip
    float* hb = ws + OFF_HRES + ((size_t)b * HIMG + y0) * WF;
    for (int idx = tid; idx < SROWS * WF; idx += 256) {   // 448
        int rr = idx / WF, i = idx - rr * WF;
        float acc = 0.0f, wsum = 0.0f;
        int j0 = 8 * i - 4;
        #pragma unroll
        for (int t = 0; t < 16; t++) {
            int j = j0 + t;
            float w_ = 8.0f - fabsf((float)t - 7.5f);
            int jh = j + 4;
            acc += w_ * sh[rr * VSTR + jh + (jh >> 3)];   // halo = 0 -> exact
            if ((unsigned)j < WIMG) wsum += w_;
        }
        hb[idx] = acc / wsum;
    }
}

// ---- per sample: minmax reduce, vertical 16-tap resize, attn norm, MSE, last-block finish ----
__global__ __launch_bounds__(256) void fused_k(float* __restrict__ ws,
                                               float* __restrict__ out) {
    __shared__ float hres[HIMG][WF + 1];   // 25,984 B
    __shared__ float wred[4];
    __shared__ float s_mn, s_mx;
    int b = blockIdx.x;
    int tid = threadIdx.x;

    // 1) reduce 14 per-strip var min/max pairs (first wave)
    if (tid < 64) {
        float mn = INFINITY, mx = 0.0f;
        if (tid < STRIPS) {
            mn = ws[OFF_BMM + 2 * (b * STRIPS + tid)];
            mx = ws[OFF_BMM + 2 * (b * STRIPS + tid) + 1];
        }
        #pragma unroll
        for (int o = 8; o > 0; o >>= 1) {
            mn = fminf(mn, __shfl_down(mn, o));
            mx = fmaxf(mx, __shfl_down(mx, o));
        }
        if (tid == 0) { s_mn = mn; s_mx = mx; }
    }

    // 2) stage hres (coalesced)
    const float* hg = ws + OFF_HRES + (size_t)b * HIMG * WF;
    for (int i = tid; i < HIMG * WF; i += 256) {
        int y = i / WF, x = i - y * WF;
        hres[y][x] = hg[i];
    }
    __syncthreads();

    float vmn = s_mn, vmx = s_mx;
    float vden = vmx - vmn;
    bool vok = vden > EPS_C;

    // 3) vertical resize -> sal (regs); attn from ZG partials (regs)
    const float* ap = ws + OFF_AP + (size_t)b * POS;
    float salv[4], attnv[4];
    float amn = INFINITY, amx = -INFINITY;
    #pragma unroll
    for (int k = 0; k < 4; k++) {
        int idx = tid + 256 * k;
        salv[k] = 0.0f; attnv[k] = 0.0f;
        if (idx < POS) {
            int yo = idx / WF, x = idx - yo * WF;
            float acc = 0.0f, wsum = 0.0f;
            int j0 = 8 * yo - 4;
            #pragma unroll
            for (int t = 0; t < 16; t++) {
                int j = j0 + t;
                float w = 8.0f - fabsf((float)t - 7.5f);
                if ((unsigned)j < HIMG) { acc += w * hres[j][x]; wsum += w; }
            }
            float sraw = acc / wsum;
            salv[k] = vok ? (sraw - vmn) / vden : 0.5f;
            float ssum = 0.0f;
            #pragma unroll
            for (int z = 0; z < ZG; z++)
                ssum += ap[(size_t)z * BATCH * POS + idx];
            float a = sqrtf(ssum * (1.0f / CF));
            attnv[k] = a;
            amn = fminf(amn, a); amx = fmaxf(amx, a);
        }
    }

    // 4) block min/max of attn
    #pragma unroll
    for (int o = 32; o > 0; o >>= 1) {
        amn = fminf(amn, __shfl_xor(amn, o));
        amx = fmaxf(amx, __shfl_xor(amx, o));
    }
    int w = tid >> 6;
    if ((tid & 63) == 0) wred[w] = amn;
    __syncthreads();
    if (tid == 0) s_mn = fminf(fminf(wred[0], wred[1]), fminf(wred[2], wred[3]));
    __syncthreads();
    if ((tid & 63) == 0) wred[w] = amx;
    __syncthreads();
    if (tid == 0) s_mx = fmaxf(fmaxf(wred[0], wred[1]), fmaxf(wred[2], wred[3]));
    __syncthreads();
    amn = s_mn; amx = s_mx;
    float aden = amx - amn;
    bool aok = aden > EPS_C;

    // 5) MSE partial
    float lsum = 0.0f;
    #pragma unroll
    for (int k = 0; k < 4; k++) {
        int idx = tid + 256 * k;
        if (idx < POS) {
            float an = aok ? (attnv[k] - amn) / aden : 0.5f;
            float d = an - salv[k];
            lsum += d * d;
        }
    }
    #pragma unroll
    for (int o = 32; o > 0; o >>= 1) lsum += __shfl_xor(lsum, o);
    if ((tid & 63) == 0) wred[w] = lsum;
    __syncthreads();

    // 6) accumulate across blocks; last finished block writes output
    if (tid == 0) {
        float part = wred[0] + wred[1] + wred[2] + wred[3];
        atomicAdd(ws + OFF_ACC, part);
        __threadfence();
        unsigned old = atomicAdd((unsigned*)ws + OFF_CNT, 1u);
        if (old == BATCH - 1) {
            float tot = atomicAdd(ws + OFF_ACC, 0.0f);  // device-coherent read
            out[0] = tot * (ALPHA_C / (float)(BATCH * POS));
        }
    }
}

extern "C" void kernel_launch(void* const* d_in, const int* in_sizes, int n_in,
                              void* d_out, int out_size, void* d_ws, size_t ws_size,
                              hipStream_t stream) {
    const float* features = (const float*)d_in[0];  // [64,512,28,28]
    const float* images   = (const float*)d_in[1];  // [64,3,224,224]
    float* ws  = (float*)d_ws;
    float* out = (float*)d_out;

    hipLaunchKernelGGL(attn_k,  dim3(ZG, BATCH),     dim3(256), 0, stream, features, ws);
    hipLaunchKernelGGL(varh_k,  dim3(STRIPS, BATCH), dim3(256), 0, stream, images, ws);
    hipLaunchKernelGGL(fused_k, dim3(BATCH),         dim3(256), 0, stream, ws, out);
}